// Round 3
// baseline (211.887 us; speedup 1.0000x reference)
//
#include <hip/hip_runtime.h>

typedef short short8 __attribute__((ext_vector_type(8)));
typedef float f32x4 __attribute__((ext_vector_type(4)));

#define NROWS 65536        // B*T = 32*2048
#define NCOMPACT 640       // compacted+padded OUT columns

__device__ __forceinline__ short f2bf(float f) {
  union { float f; unsigned u; } c; c.f = f;
  unsigned r = (c.u + 0x7fffu + ((c.u >> 16) & 1u)) >> 16;
  return (short)r;
}

// Map compacted column n -> original W3/b3 column (or -1 for zero pad).
// Layout: [0,32): logscales[32+j]  [32,64): biases[32+j]  [64,72): logits[k]
//         [72,96): pad  [96,352): mu[k][32+j]  [352,608): logstd[k][32+j]  [608,640): pad
__device__ __forceinline__ int w3col(int n) {
  if (n < 32)  return 32 + n;
  if (n < 64)  return 96 + (n - 32);
  if (n < 72)  return 128 + (n - 64);
  if (n < 96)  return -1;
  if (n < 352) { int q = n - 96;  return 168 + (q >> 5) * 64 + (q & 31); }
  if (n < 608) { int q = n - 352; return 680 + (q >> 5) * 64 + (q & 31); }
  return -1;
}

__global__ __launch_bounds__(256) void prep_x_kernel(const float* __restrict__ x,
                                                     short* __restrict__ xc) {
  int t = blockIdx.x * 256 + threadIdx.x;
  if (t >= NROWS * 4) return;
  int row = t >> 2, seg = t & 3;
  const float* src = x + (size_t)row * 64 + seg * 8;
  short8 v;
#pragma unroll
  for (int i = 0; i < 8; ++i) v[i] = f2bf(src[i]);
  *(short8*)(xc + (size_t)row * 32 + seg * 8) = v;
}

__global__ __launch_bounds__(256) void prep_w_kernel(
    const float* __restrict__ W1, const float* __restrict__ W2,
    const float* __restrict__ W3, const float* __restrict__ b3,
    short* __restrict__ w1t, short* __restrict__ w2t,
    short* __restrict__ w3t, float* __restrict__ b3c) {
  const int NW1 = 512 * 32, NW2 = 512 * 512, NW3 = NCOMPACT * 512;
  int t = blockIdx.x * 256 + threadIdx.x;
  if (t < NW1) {
    int n = t >> 5, k = t & 31;
    w1t[t] = f2bf(W1[k * 512 + n]);
  } else if (t < NW1 + NW2) {
    int i = t - NW1; int n = i >> 9, k = i & 511;
    w2t[i] = f2bf(W2[k * 512 + n]);
  } else if (t < NW1 + NW2 + NW3) {
    int i = t - NW1 - NW2; int n = i >> 9, k = i & 511;
    int c = w3col(n);
    w3t[i] = (c >= 0) ? f2bf(W3[(size_t)k * 1160 + c]) : (short)0;
  } else if (t < NW1 + NW2 + NW3 + NCOMPACT) {
    int n = t - NW1 - NW2 - NW3;
    int c = w3col(n);
    b3c[n] = (c >= 0) ? b3[c] : 0.0f;
  }
}

// C[M][N] = act(A[M][K] @ B^T[N][K] + bias[N]); 128x128 tile, 4 waves, 16x16x32 bf16 MFMA.
// 1D grid + bijective XCD-chunked swizzle, n-fastest work order: each XCD gets a
// contiguous m-range so the NT blocks sharing an A panel hit the same L2.
template <int BK, int NT, bool RELU, bool OUT_BF16>
__global__ __launch_bounds__(256) void gemm_kernel(
    const short* __restrict__ A, const short* __restrict__ B,
    const float* __restrict__ bias, void* __restrict__ C, int K, int N) {
  __shared__ short As[128 * BK];
  __shared__ short Bs[128 * BK];
  const int tid = threadIdx.x;
  const int cpx = gridDim.x >> 3;
  const int s = blockIdx.x;
  const int w = (s & 7) * cpx + (s >> 3);       // work id: XCD-contiguous
  const int m0 = (w / NT) * 128, n0 = (w % NT) * 128;
  const int lane = tid & 63, wid = tid >> 6;
  const int wm = (wid >> 1) * 64, wn = (wid & 1) * 64;
  const int lr = lane & 15, lk = (lane >> 4) * 8;
  constexpr int CPR = BK / 8;
  constexpr int SWM = CPR - 1;
  constexpr int NCHUNK = 128 * CPR;

  f32x4 acc[4][4] = {};

  for (int kt = 0; kt < K; kt += BK) {
    for (int base = wid * 64; base < NCHUNK; base += 256) {
      int c = base + lane;
      int row = c / CPR;
      int kb = (c % CPR) << 4;
      int skb = kb ^ ((row & SWM) << 4);
      const char* ga = (const char*)(A + (size_t)(m0 + row) * K + kt) + skb;
      const char* gb = (const char*)(B + (size_t)(n0 + row) * K + kt) + skb;
      __builtin_amdgcn_global_load_lds(
          (const __attribute__((address_space(1))) void*)ga,
          (__attribute__((address_space(3))) void*)((char*)As + (size_t)base * 16), 16, 0, 0);
      __builtin_amdgcn_global_load_lds(
          (const __attribute__((address_space(1))) void*)gb,
          (__attribute__((address_space(3))) void*)((char*)Bs + (size_t)base * 16), 16, 0, 0);
    }
    __syncthreads();
#pragma unroll
    for (int ks = 0; ks < BK; ks += 32) {
      short8 af[4], bf_[4];
#pragma unroll
      for (int mi = 0; mi < 4; ++mi) {
        int row = wm + mi * 16 + lr;
        int k = (ks + lk) ^ ((row & SWM) << 3);
        af[mi] = *(const short8*)(&As[row * BK + k]);
      }
#pragma unroll
      for (int ni = 0; ni < 4; ++ni) {
        int row = wn + ni * 16 + lr;
        int k = (ks + lk) ^ ((row & SWM) << 3);
        bf_[ni] = *(const short8*)(&Bs[row * BK + k]);
      }
#pragma unroll
      for (int mi = 0; mi < 4; ++mi)
#pragma unroll
        for (int ni = 0; ni < 4; ++ni)
          acc[mi][ni] = __builtin_amdgcn_mfma_f32_16x16x32_bf16(
              af[mi], bf_[ni], acc[mi][ni], 0, 0, 0);
    }
    __syncthreads();
  }

#pragma unroll
  for (int ni = 0; ni < 4; ++ni) {
    int col = n0 + wn + ni * 16 + lr;
    float bv = bias[col];
#pragma unroll
    for (int mi = 0; mi < 4; ++mi) {
#pragma unroll
      for (int j = 0; j < 4; ++j) {
        int row = m0 + wm + mi * 16 + (lane >> 4) * 4 + j;
        float v = acc[mi][ni][j] + bv;
        if (RELU) v = fmaxf(v, 0.0f);
        if (OUT_BF16) ((short*)C)[(size_t)row * N + col] = f2bf(v);
        else          ((float*)C)[(size_t)row * N + col] = v;
      }
    }
  }
}

// GEMM3 + mixture-CDF transform, fused. Block = 32 rows x 640 cols, 4 waves,
// wave w owns cols [w*160, w*160+160) (2 m-frags x 10 n-frags, acc 80 VGPR).
// BK=32 single-buffered global_load_lds staging (A 2KB + B 40KB), source-swizzled.
// Epilogue: acc+bias -> padded LDS tile (16 rows x 644 f32, two halves) -> transform
// math per (row, j) -> write x_out/log_det directly. params never touch HBM.
#define PSTR 644
__global__ __launch_bounds__(256, 2) void gemm3_fused_kernel(
    const short* __restrict__ A,      // h2 bf16 [NROWS][512]
    const short* __restrict__ Bw,     // w3t bf16 [640][512]
    const float* __restrict__ b3c,    // [640]
    const float* __restrict__ x,      // fp32 [NROWS][64]
    float* __restrict__ out) {
  __shared__ __attribute__((aligned(16))) char ldsbuf[45056];
  short* As = (short*)ldsbuf;                 // [32][32]
  short* Bs = (short*)(ldsbuf + 2048);        // [640][32]
  const int tid = threadIdx.x;
  const int m0 = blockIdx.x * 32;
  const int lane = tid & 63, wid = tid >> 6;
  const int lr = lane & 15, hi = lane >> 4, lk = hi * 8;

  f32x4 acc[2][10] = {};

  for (int kt = 0; kt < 512; kt += 32) {
    // stage A (chunks 0..127) and B (chunks 128..2687); wave-uniform segments
    for (int base = wid * 64; base < 2688; base += 256) {
      int c = base + lane;
      char* dst = ldsbuf + (size_t)base * 16;   // HW adds lane*16
      if (base < 128) {
        int row = c >> 2;
        int kb = (c & 3) << 4;
        int skb = kb ^ ((row & 3) << 4);
        const char* ga = (const char*)(A + (size_t)(m0 + row) * 512 + kt) + skb;
        __builtin_amdgcn_global_load_lds(
            (const __attribute__((address_space(1))) void*)ga,
            (__attribute__((address_space(3))) void*)dst, 16, 0, 0);
      } else {
        int q = c - 128;
        int row = q >> 2;
        int kb = (q & 3) << 4;
        int skb = kb ^ ((row & 3) << 4);
        const char* gb = (const char*)(Bw + (size_t)row * 512 + kt) + skb;
        __builtin_amdgcn_global_load_lds(
            (const __attribute__((address_space(1))) void*)gb,
            (__attribute__((address_space(3))) void*)dst, 16, 0, 0);
      }
    }
    __syncthreads();
    short8 af[2];
#pragma unroll
    for (int mi = 0; mi < 2; ++mi) {
      int row = mi * 16 + lr;
      int k = lk ^ ((row & 3) << 3);
      af[mi] = *(const short8*)(&As[row * 32 + k]);
    }
#pragma unroll
    for (int ni = 0; ni < 10; ++ni) {
      int brow = wid * 160 + ni * 16 + lr;
      int k = lk ^ ((brow & 3) << 3);
      short8 bf_ = *(const short8*)(&Bs[brow * 32 + k]);
      acc[0][ni] = __builtin_amdgcn_mfma_f32_16x16x32_bf16(af[0], bf_, acc[0][ni], 0, 0, 0);
      acc[1][ni] = __builtin_amdgcn_mfma_f32_16x16x32_bf16(af[1], bf_, acc[1][ni], 0, 0, 0);
    }
    __syncthreads();
  }

  // ---- fused transform epilogue, two 16-row halves ----
  float* plds = (float*)ldsbuf;                 // [16][PSTR]
  float* xo  = out;
  float* ldo = out + (size_t)NROWS * 64;
#pragma unroll
  for (int h = 0; h < 2; ++h) {
    __syncthreads();
#pragma unroll
    for (int ni = 0; ni < 10; ++ni) {
      int col = wid * 160 + ni * 16 + lr;
      float bv = b3c[col];
#pragma unroll
      for (int j = 0; j < 4; ++j) {
        int rl = hi * 4 + j;
        plds[rl * PSTR + col] = acc[h][ni][j] + bv;
      }
    }
    __syncthreads();
#pragma unroll
    for (int it = 0; it < 2; ++it) {
      int t = tid + it * 256;
      int rl = t >> 5, j = t & 31;
      const float* p = plds + rl * PSTR;
      int grow = m0 + h * 16 + rl;

      float lg[8];
#pragma unroll
      for (int k = 0; k < 8; ++k) lg[k] = p[64 + k];
      float mx = lg[0];
#pragma unroll
      for (int k = 1; k < 8; ++k) mx = fmaxf(mx, lg[k]);
      float wgt[8], wsum = 0.0f;
#pragma unroll
      for (int k = 0; k < 8; ++k) { wgt[k] = expf(lg[k] - mx); wsum += wgt[k]; }

      float xd = x[(size_t)grow * 64 + 32 + j];
      float zs = 0.0f, ps = 0.0f;
#pragma unroll
      for (int k = 0; k < 8; ++k) {
        float mu   = p[96 + k * 32 + j];
        float lstd = p[352 + k * 32 + j];
        float istd = expf(-lstd);
        float u = (xd - mu) * istd;
        float cdf = 0.5f * (1.0f + erff(u * 0.70710678118654752f));
        zs += wgt[k] * cdf;
        ps += wgt[k] * expf(-0.5f * u * u) * istd;
      }
      float z  = zs / wsum;
      float pm = (ps / wsum) * 0.39894228040143268f;
      float logz = logf(z), log1mz = logf(1.0f - z);
      float ls = p[j], bv = p[32 + j];
      float xs = logz - log1mz;
      float outv = xs * expf(ls) + bv;
      float ld = logf(pm) - logz - log1mz + ls;

      size_t base = (size_t)grow * 64;
      xo[base + j]       = x[base + j];
      xo[base + 32 + j]  = outv;
      ldo[base + j]      = 0.0f;
      ldo[base + 32 + j] = ld;
    }
  }
}

extern "C" void kernel_launch(void* const* d_in, const int* in_sizes, int n_in,
                              void* d_out, int out_size, void* d_ws, size_t ws_size,
                              hipStream_t stream) {
  const float* x  = (const float*)d_in[0];
  const float* W1 = (const float*)d_in[1];
  const float* b1 = (const float*)d_in[2];
  const float* W2 = (const float*)d_in[3];
  const float* b2 = (const float*)d_in[4];
  const float* W3 = (const float*)d_in[5];
  const float* b3 = (const float*)d_in[6];
  char* ws = (char*)d_ws;

  // Workspace (~134 MB, no aliasing needed: params never materialized)
  short* xc  = (short*)ws;                          // 4 MB   bf16 [65536][32]
  short* h1  = (short*)(ws + 4194304);              // 64 MB  bf16 [65536][512]
  short* h2  = (short*)(ws + 71303168);             // 64 MB  bf16 [65536][512]
  short* w1t = (short*)(ws + 138412032);            // 32 KB  bf16 [512][32]
  short* w2t = (short*)(ws + 138444800);            // 512 KB bf16 [512][512]
  short* w3t = (short*)(ws + 138969088);            // 640 KB bf16 [640][512]
  float* b3c = (float*)(ws + 139624448);            // 2.5 KB fp32 [640]
  float* out = (float*)d_out;

  prep_x_kernel<<<(NROWS * 4) / 256, 256, 0, stream>>>(x, xc);
  {
    int total = 512 * 32 + 512 * 512 + NCOMPACT * 512 + NCOMPACT;
    prep_w_kernel<<<(total + 255) / 256, 256, 0, stream>>>(W1, W2, W3, b3, w1t, w2t, w3t, b3c);
  }
  gemm_kernel<32, 4, true, true><<<2048, 256, 0, stream>>>(xc, w1t, b1, h1, 32, 512);
  gemm_kernel<64, 4, true, true><<<2048, 256, 0, stream>>>(h1, w2t, b2, h2, 512, 512);
  gemm3_fused_kernel<<<NROWS / 32, 256, 0, stream>>>(h2, w3t, b3c, x, out);
}

// Round 4
// 179.864 us; speedup vs baseline: 1.1780x; 1.1780x over previous
//
#include <hip/hip_runtime.h>

typedef short short8 __attribute__((ext_vector_type(8)));
typedef float f32x4 __attribute__((ext_vector_type(4)));

#define NROWS 65536        // B*T = 32*2048
#define NCOMPACT 640       // compacted+padded OUT columns

__device__ __forceinline__ short f2bf(float f) {
  union { float f; unsigned u; } c; c.f = f;
  unsigned r = (c.u + 0x7fffu + ((c.u >> 16) & 1u)) >> 16;
  return (short)r;
}

// Map compacted column n -> original W3/b3 column (or -1 for zero pad).
__device__ __forceinline__ int w3col(int n) {
  if (n < 32)  return 32 + n;
  if (n < 64)  return 96 + (n - 32);
  if (n < 72)  return 128 + (n - 64);
  if (n < 96)  return -1;
  if (n < 352) { int q = n - 96;  return 168 + (q >> 5) * 64 + (q & 31); }
  if (n < 608) { int q = n - 352; return 680 + (q >> 5) * 64 + (q & 31); }
  return -1;
}

__global__ __launch_bounds__(256) void prep_x_kernel(const float* __restrict__ x,
                                                     short* __restrict__ xc) {
  int t = blockIdx.x * 256 + threadIdx.x;
  if (t >= NROWS * 4) return;
  int row = t >> 2, seg = t & 3;
  const float* src = x + (size_t)row * 64 + seg * 8;
  short8 v;
#pragma unroll
  for (int i = 0; i < 8; ++i) v[i] = f2bf(src[i]);
  *(short8*)(xc + (size_t)row * 32 + seg * 8) = v;
}

__global__ __launch_bounds__(256) void prep_w_kernel(
    const float* __restrict__ W1, const float* __restrict__ W2,
    const float* __restrict__ W3, const float* __restrict__ b3,
    short* __restrict__ w1t, short* __restrict__ w2t,
    short* __restrict__ w3t, float* __restrict__ b3c) {
  const int NW1 = 512 * 32, NW2 = 512 * 512, NW3 = NCOMPACT * 512;
  int t = blockIdx.x * 256 + threadIdx.x;
  if (t < NW1) {
    int n = t >> 5, k = t & 31;
    w1t[t] = f2bf(W1[k * 512 + n]);
  } else if (t < NW1 + NW2) {
    int i = t - NW1; int n = i >> 9, k = i & 511;
    w2t[i] = f2bf(W2[k * 512 + n]);
  } else if (t < NW1 + NW2 + NW3) {
    int i = t - NW1 - NW2; int n = i >> 9, k = i & 511;
    int c = w3col(n);
    w3t[i] = (c >= 0) ? f2bf(W3[(size_t)k * 1160 + c]) : (short)0;
  } else if (t < NW1 + NW2 + NW3 + NCOMPACT) {
    int n = t - NW1 - NW2 - NW3;
    int c = w3col(n);
    b3c[n] = (c >= 0) ? b3[c] : 0.0f;
  }
}

// C[M][N] = act(A[M][K] @ B^T[N][K] + bias[N]); 128x128 tile, 4 waves.
// 1D grid + bijective XCD-chunked swizzle, n-fastest work order.
template <int BK, int NT, bool RELU, bool OUT_BF16>
__global__ __launch_bounds__(256) void gemm_kernel(
    const short* __restrict__ A, const short* __restrict__ B,
    const float* __restrict__ bias, void* __restrict__ C, int K, int N) {
  __shared__ short As[128 * BK];
  __shared__ short Bs[128 * BK];
  const int tid = threadIdx.x;
  const int cpx = gridDim.x >> 3;
  const int s = blockIdx.x;
  const int w = (s & 7) * cpx + (s >> 3);
  const int m0 = (w / NT) * 128, n0 = (w % NT) * 128;
  const int lane = tid & 63, wid = tid >> 6;
  const int wm = (wid >> 1) * 64, wn = (wid & 1) * 64;
  const int lr = lane & 15, lk = (lane >> 4) * 8;
  constexpr int CPR = BK / 8;
  constexpr int SWM = CPR - 1;
  constexpr int NCHUNK = 128 * CPR;

  f32x4 acc[4][4] = {};

  for (int kt = 0; kt < K; kt += BK) {
    for (int base = wid * 64; base < NCHUNK; base += 256) {
      int c = base + lane;
      int row = c / CPR;
      int kb = (c % CPR) << 4;
      int skb = kb ^ ((row & SWM) << 4);
      const char* ga = (const char*)(A + (size_t)(m0 + row) * K + kt) + skb;
      const char* gb = (const char*)(B + (size_t)(n0 + row) * K + kt) + skb;
      __builtin_amdgcn_global_load_lds(
          (const __attribute__((address_space(1))) void*)ga,
          (__attribute__((address_space(3))) void*)((char*)As + (size_t)base * 16), 16, 0, 0);
      __builtin_amdgcn_global_load_lds(
          (const __attribute__((address_space(1))) void*)gb,
          (__attribute__((address_space(3))) void*)((char*)Bs + (size_t)base * 16), 16, 0, 0);
    }
    __syncthreads();
#pragma unroll
    for (int ks = 0; ks < BK; ks += 32) {
      short8 af[4], bf_[4];
#pragma unroll
      for (int mi = 0; mi < 4; ++mi) {
        int row = wm + mi * 16 + lr;
        int k = (ks + lk) ^ ((row & SWM) << 3);
        af[mi] = *(const short8*)(&As[row * BK + k]);
      }
#pragma unroll
      for (int ni = 0; ni < 4; ++ni) {
        int row = wn + ni * 16 + lr;
        int k = (ks + lk) ^ ((row & SWM) << 3);
        bf_[ni] = *(const short8*)(&Bs[row * BK + k]);
      }
#pragma unroll
      for (int mi = 0; mi < 4; ++mi)
#pragma unroll
        for (int ni = 0; ni < 4; ++ni)
          acc[mi][ni] = __builtin_amdgcn_mfma_f32_16x16x32_bf16(
              af[mi], bf_[ni], acc[mi][ni], 0, 0, 0);
    }
    __syncthreads();
  }

#pragma unroll
  for (int ni = 0; ni < 4; ++ni) {
    int col = n0 + wn + ni * 16 + lr;
    float bv = bias[col];
#pragma unroll
    for (int mi = 0; mi < 4; ++mi) {
#pragma unroll
      for (int j = 0; j < 4; ++j) {
        int row = m0 + wm + mi * 16 + (lane >> 4) * 4 + j;
        float v = acc[mi][ni][j] + bv;
        if (RELU) v = fmaxf(v, 0.0f);
        if (OUT_BF16) ((short*)C)[(size_t)row * N + col] = f2bf(v);
        else          ((float*)C)[(size_t)row * N + col] = v;
      }
    }
  }
}

// GEMM3 + mixture-CDF transform, fused. Block = 64 rows x 640 cols, 8 waves (2Mx4N).
// Wave (wr,wc): rows [wr*32,+32), cols [wc*160,+160) -> acc[2][10] (80 VGPR).
// BK=32 global_load_lds staging, source-side XOR swizzle g(row)=(row>>1)&3
// (cycles all 8 16B bank-slots over 16 consecutive rows -> free 2-way aliasing).
// Epilogue: 4x 16-row quarters through padded LDS -> transform -> direct d_out write.
#define PSTR 644
__global__ __launch_bounds__(512, 4) void gemm3_fused_kernel(
    const short* __restrict__ A,      // h2 bf16 [NROWS][512]
    const short* __restrict__ Bw,     // w3t bf16 [640][512]
    const float* __restrict__ b3c,    // [640]
    const float* __restrict__ x,      // fp32 [NROWS][64]
    float* __restrict__ out) {
  __shared__ __attribute__((aligned(16))) char ldsbuf[45056];
  short* As = (short*)ldsbuf;                 // [64][32]
  short* Bs = (short*)(ldsbuf + 4096);        // [640][32]
  const int tid = threadIdx.x;
  const int m0 = blockIdx.x * 64;
  const int lane = tid & 63, wid = tid >> 6;
  const int wr = wid >> 2, wc = wid & 3;
  const int lr = lane & 15, hi = lane >> 4, lk = hi * 8;

  f32x4 acc[2][10] = {};

  for (int kt = 0; kt < 512; kt += 32) {
    // stage: A chunks [0,256), B chunks [256,2816); wave-uniform 64-chunk segments
    for (int base = wid * 64; base < 2816; base += 512) {
      int c = base + lane;
      char* dst = ldsbuf + (size_t)base * 16;   // HW adds lane*16
      if (base < 256) {
        int row = c >> 2;
        int skb = (((c & 3) ^ ((row >> 1) & 3)) << 4);
        const char* ga = (const char*)(A + (size_t)(m0 + row) * 512 + kt) + skb;
        __builtin_amdgcn_global_load_lds(
            (const __attribute__((address_space(1))) void*)ga,
            (__attribute__((address_space(3))) void*)dst, 16, 0, 0);
      } else {
        int q = c - 256;
        int row = q >> 2;
        int skb = (((q & 3) ^ ((row >> 1) & 3)) << 4);
        const char* gb = (const char*)(Bw + (size_t)row * 512 + kt) + skb;
        __builtin_amdgcn_global_load_lds(
            (const __attribute__((address_space(1))) void*)gb,
            (__attribute__((address_space(3))) void*)dst, 16, 0, 0);
      }
    }
    __syncthreads();
    short8 af[2];
#pragma unroll
    for (int mi = 0; mi < 2; ++mi) {
      int row = wr * 32 + mi * 16 + lr;
      int k = lk ^ (((row >> 1) & 3) << 3);
      af[mi] = *(const short8*)(&As[row * 32 + k]);
    }
#pragma unroll
    for (int ni = 0; ni < 10; ++ni) {
      int brow = wc * 160 + ni * 16 + lr;
      int k = lk ^ (((brow >> 1) & 3) << 3);
      short8 bf_ = *(const short8*)(&Bs[brow * 32 + k]);
      acc[0][ni] = __builtin_amdgcn_mfma_f32_16x16x32_bf16(af[0], bf_, acc[0][ni], 0, 0, 0);
      acc[1][ni] = __builtin_amdgcn_mfma_f32_16x16x32_bf16(af[1], bf_, acc[1][ni], 0, 0, 0);
    }
    __syncthreads();
  }

  // ---- fused transform epilogue: four 16-row quarters ----
  float* plds = (float*)ldsbuf;                 // [16][PSTR]
  float* xo  = out;
  float* ldo = out + (size_t)NROWS * 64;
#pragma unroll
  for (int q = 0; q < 4; ++q) {
    if (q) __syncthreads();
    if (wr == (q >> 1)) {
      constexpr int dummy = 0; (void)dummy;
#pragma unroll
      for (int ni = 0; ni < 10; ++ni) {
        int col = wc * 160 + ni * 16 + lr;
        float bv = b3c[col];
#pragma unroll
        for (int j = 0; j < 4; ++j) {
          float v = (q & 1) ? acc[1][ni][j] : acc[0][ni][j];
          plds[(hi * 4 + j) * PSTR + col] = v + bv;
        }
      }
    }
    __syncthreads();
    {
      int rl = tid >> 5, j = tid & 31;          // 512 threads -> rl 0..15, j 0..31
      const float* p = plds + rl * PSTR;
      int grow = m0 + q * 16 + rl;

      float lg[8];
#pragma unroll
      for (int k = 0; k < 8; ++k) lg[k] = p[64 + k];
      float mx = lg[0];
#pragma unroll
      for (int k = 1; k < 8; ++k) mx = fmaxf(mx, lg[k]);
      float wgt[8], wsum = 0.0f;
#pragma unroll
      for (int k = 0; k < 8; ++k) { wgt[k] = expf(lg[k] - mx); wsum += wgt[k]; }

      float xd = x[(size_t)grow * 64 + 32 + j];
      float zs = 0.0f, ps = 0.0f;
#pragma unroll
      for (int k = 0; k < 8; ++k) {
        float mu   = p[96 + k * 32 + j];
        float lstd = p[352 + k * 32 + j];
        float istd = expf(-lstd);
        float u = (xd - mu) * istd;
        float cdf = 0.5f * (1.0f + erff(u * 0.70710678118654752f));
        zs += wgt[k] * cdf;
        ps += wgt[k] * expf(-0.5f * u * u) * istd;
      }
      float z  = zs / wsum;
      float pm = (ps / wsum) * 0.39894228040143268f;
      float logz = logf(z), log1mz = logf(1.0f - z);
      float ls = p[j], bv = p[32 + j];
      float xs = logz - log1mz;
      float outv = xs * expf(ls) + bv;
      float ld = logf(pm) - logz - log1mz + ls;

      size_t base = (size_t)grow * 64;
      xo[base + j]       = x[base + j];
      xo[base + 32 + j]  = outv;
      ldo[base + j]      = 0.0f;
      ldo[base + 32 + j] = ld;
    }
  }
}

extern "C" void kernel_launch(void* const* d_in, const int* in_sizes, int n_in,
                              void* d_out, int out_size, void* d_ws, size_t ws_size,
                              hipStream_t stream) {
  const float* x  = (const float*)d_in[0];
  const float* W1 = (const float*)d_in[1];
  const float* b1 = (const float*)d_in[2];
  const float* W2 = (const float*)d_in[3];
  const float* b2 = (const float*)d_in[4];
  const float* W3 = (const float*)d_in[5];
  const float* b3 = (const float*)d_in[6];
  char* ws = (char*)d_ws;

  short* xc  = (short*)ws;                          // 4 MB   bf16 [65536][32]
  short* h1  = (short*)(ws + 4194304);              // 64 MB  bf16 [65536][512]
  short* h2  = (short*)(ws + 71303168);             // 64 MB  bf16 [65536][512]
  short* w1t = (short*)(ws + 138412032);            // 32 KB  bf16 [512][32]
  short* w2t = (short*)(ws + 138444800);            // 512 KB bf16 [512][512]
  short* w3t = (short*)(ws + 138969088);            // 640 KB bf16 [640][512]
  float* b3c = (float*)(ws + 139624448);            // 2.5 KB fp32 [640]
  float* out = (float*)d_out;

  prep_x_kernel<<<(NROWS * 4) / 256, 256, 0, stream>>>(x, xc);
  {
    int total = 512 * 32 + 512 * 512 + NCOMPACT * 512 + NCOMPACT;
    prep_w_kernel<<<(total + 255) / 256, 256, 0, stream>>>(W1, W2, W3, b3, w1t, w2t, w3t, b3c);
  }
  gemm_kernel<32, 4, true, true><<<2048, 256, 0, stream>>>(xc, w1t, b1, h1, 32, 512);
  gemm_kernel<64, 4, true, true><<<2048, 256, 0, stream>>>(h1, w2t, b2, h2, 512, 512);
  gemm3_fused_kernel<<<NROWS / 64, 512, 0, stream>>>(h2, w3t, b3c, x, out);
}

// Round 5
// 146.763 us; speedup vs baseline: 1.4437x; 1.2255x over previous
//
#include <hip/hip_runtime.h>

typedef short short8 __attribute__((ext_vector_type(8)));
typedef float f32x4 __attribute__((ext_vector_type(4)));

#define NROWS 65536        // B*T = 32*2048
#define NCOMPACT 640       // compacted+padded OUT columns

__device__ __forceinline__ short f2bf(float f) {
  union { float f; unsigned u; } c; c.f = f;
  unsigned r = (c.u + 0x7fffu + ((c.u >> 16) & 1u)) >> 16;
  return (short)r;
}

__device__ __forceinline__ float fastrcp(float a) {
  float r; asm("v_rcp_f32 %0, %1" : "=v"(r) : "v"(a)); return r;
}

// Map compacted column n -> original W3/b3 column (or -1 for zero pad).
__device__ __forceinline__ int w3col(int n) {
  if (n < 32)  return 32 + n;
  if (n < 64)  return 96 + (n - 32);
  if (n < 72)  return 128 + (n - 64);
  if (n < 96)  return -1;
  if (n < 352) { int q = n - 96;  return 168 + (q >> 5) * 64 + (q & 31); }
  if (n < 608) { int q = n - 352; return 680 + (q >> 5) * 64 + (q & 31); }
  return -1;
}

__global__ __launch_bounds__(256) void prep_x_kernel(const float* __restrict__ x,
                                                     short* __restrict__ xc) {
  int t = blockIdx.x * 256 + threadIdx.x;
  if (t >= NROWS * 4) return;
  int row = t >> 2, seg = t & 3;
  const float* src = x + (size_t)row * 64 + seg * 8;
  short8 v;
#pragma unroll
  for (int i = 0; i < 8; ++i) v[i] = f2bf(src[i]);
  *(short8*)(xc + (size_t)row * 32 + seg * 8) = v;
}

__global__ __launch_bounds__(256) void prep_w_kernel(
    const float* __restrict__ W1, const float* __restrict__ W2,
    const float* __restrict__ W3, const float* __restrict__ b3,
    short* __restrict__ w1t, short* __restrict__ w2t,
    short* __restrict__ w3t, float* __restrict__ b3c) {
  const int NW1 = 512 * 32, NW2 = 512 * 512, NW3 = NCOMPACT * 512;
  int t = blockIdx.x * 256 + threadIdx.x;
  if (t < NW1) {
    int n = t >> 5, k = t & 31;
    w1t[t] = f2bf(W1[k * 512 + n]);
  } else if (t < NW1 + NW2) {
    int i = t - NW1; int n = i >> 9, k = i & 511;
    w2t[i] = f2bf(W2[k * 512 + n]);
  } else if (t < NW1 + NW2 + NW3) {
    int i = t - NW1 - NW2; int n = i >> 9, k = i & 511;
    int c = w3col(n);
    w3t[i] = (c >= 0) ? f2bf(W3[(size_t)k * 1160 + c]) : (short)0;
  } else if (t < NW1 + NW2 + NW3 + NCOMPACT) {
    int n = t - NW1 - NW2 - NW3;
    int c = w3col(n);
    b3c[n] = (c >= 0) ? b3[c] : 0.0f;
  }
}

// C[M][N] = act(A[M][K] @ B^T[N][K] + bias[N]); 128x128 tile, 4 waves.
// 1D grid + bijective XCD-chunked swizzle, n-fastest work order.
template <int BK, int NT, bool RELU, bool OUT_BF16>
__global__ __launch_bounds__(256) void gemm_kernel(
    const short* __restrict__ A, const short* __restrict__ B,
    const float* __restrict__ bias, void* __restrict__ C, int K, int N) {
  __shared__ short As[128 * BK];
  __shared__ short Bs[128 * BK];
  const int tid = threadIdx.x;
  const int cpx = gridDim.x >> 3;
  const int s = blockIdx.x;
  const int w = (s & 7) * cpx + (s >> 3);
  const int m0 = (w / NT) * 128, n0 = (w % NT) * 128;
  const int lane = tid & 63, wid = tid >> 6;
  const int wm = (wid >> 1) * 64, wn = (wid & 1) * 64;
  const int lr = lane & 15, lk = (lane >> 4) * 8;
  constexpr int CPR = BK / 8;
  constexpr int SWM = CPR - 1;
  constexpr int NCHUNK = 128 * CPR;

  f32x4 acc[4][4] = {};

  for (int kt = 0; kt < K; kt += BK) {
    for (int base = wid * 64; base < NCHUNK; base += 256) {
      int c = base + lane;
      int row = c / CPR;
      int kb = (c % CPR) << 4;
      int skb = kb ^ ((row & SWM) << 4);
      const char* ga = (const char*)(A + (size_t)(m0 + row) * K + kt) + skb;
      const char* gb = (const char*)(B + (size_t)(n0 + row) * K + kt) + skb;
      __builtin_amdgcn_global_load_lds(
          (const __attribute__((address_space(1))) void*)ga,
          (__attribute__((address_space(3))) void*)((char*)As + (size_t)base * 16), 16, 0, 0);
      __builtin_amdgcn_global_load_lds(
          (const __attribute__((address_space(1))) void*)gb,
          (__attribute__((address_space(3))) void*)((char*)Bs + (size_t)base * 16), 16, 0, 0);
    }
    __syncthreads();
#pragma unroll
    for (int ks = 0; ks < BK; ks += 32) {
      short8 af[4], bf_[4];
#pragma unroll
      for (int mi = 0; mi < 4; ++mi) {
        int row = wm + mi * 16 + lr;
        int k = (ks + lk) ^ ((row & SWM) << 3);
        af[mi] = *(const short8*)(&As[row * BK + k]);
      }
#pragma unroll
      for (int ni = 0; ni < 4; ++ni) {
        int row = wn + ni * 16 + lr;
        int k = (ks + lk) ^ ((row & SWM) << 3);
        bf_[ni] = *(const short8*)(&Bs[row * BK + k]);
      }
#pragma unroll
      for (int mi = 0; mi < 4; ++mi)
#pragma unroll
        for (int ni = 0; ni < 4; ++ni)
          acc[mi][ni] = __builtin_amdgcn_mfma_f32_16x16x32_bf16(
              af[mi], bf_[ni], acc[mi][ni], 0, 0, 0);
    }
    __syncthreads();
  }

#pragma unroll
  for (int ni = 0; ni < 4; ++ni) {
    int col = n0 + wn + ni * 16 + lr;
    float bv = bias[col];
#pragma unroll
    for (int mi = 0; mi < 4; ++mi) {
#pragma unroll
      for (int j = 0; j < 4; ++j) {
        int row = m0 + wm + mi * 16 + (lane >> 4) * 4 + j;
        float v = acc[mi][ni][j] + bv;
        if (RELU) v = fmaxf(v, 0.0f);
        if (OUT_BF16) ((short*)C)[(size_t)row * N + col] = f2bf(v);
        else          ((float*)C)[(size_t)row * N + col] = v;
      }
    }
  }
}

// GEMM3 + mixture-CDF transform, fused. Block = 128 rows x 640 cols, 8 waves (2Mx4N),
// wave = 64 rows x 160 cols -> acc[4][10] (160 AGPR). Double-buffered BK=32 staging
// (2 x 48KB LDS): STAGE(next) issued before COMPUTE(cur); __syncthreads' implicit
// vmcnt drain is the only wait -> L2 latency hides under 40 MFMA/wave.
// Source-side XOR swizzle g(row)=(row>>1)&3 (2-way LDS aliasing = free).
// Epilogue: 8x 16-row quarters through padded LDS -> fast-math transform -> d_out.
#define PSTR 644
#define BUF1 49152
__global__ __launch_bounds__(512, 2) void gemm3_fused_kernel(
    const short* __restrict__ A,      // h2 bf16 [NROWS][512]
    const short* __restrict__ Bw,     // w3t bf16 [640][512]
    const float* __restrict__ b3c,    // [640]
    const float* __restrict__ x,      // fp32 [NROWS][64]
    float* __restrict__ out) {
  __shared__ __attribute__((aligned(16))) char lds[98304];
  const int tid = threadIdx.x;
  const int m0 = blockIdx.x * 128;
  const int lane = tid & 63, wid = tid >> 6;
  const int wr = wid >> 2, wc = wid & 3;
  const int lr = lane & 15, hi = lane >> 4, lk = hi * 8;

  f32x4 acc[4][10] = {};

  auto STAGE = [&](int bo, int kt) {
#pragma unroll
    for (int base = wid * 64; base < 3072; base += 512) {
      int c = base + lane;
      char* dst = lds + bo + (size_t)base * 16;   // HW adds lane*16
      if (base < 512) {                           // A chunks [0,512)
        int row = c >> 2;
        int skb = ((c & 3) ^ ((row >> 1) & 3)) << 4;
        const char* ga = (const char*)(A + (size_t)(m0 + row) * 512 + kt) + skb;
        __builtin_amdgcn_global_load_lds(
            (const __attribute__((address_space(1))) void*)ga,
            (__attribute__((address_space(3))) void*)dst, 16, 0, 0);
      } else {                                    // B chunks [512,3072)
        int q = c - 512;
        int row = q >> 2;
        int skb = ((q & 3) ^ ((row >> 1) & 3)) << 4;
        const char* gb = (const char*)(Bw + (size_t)row * 512 + kt) + skb;
        __builtin_amdgcn_global_load_lds(
            (const __attribute__((address_space(1))) void*)gb,
            (__attribute__((address_space(3))) void*)dst, 16, 0, 0);
      }
    }
  };

  auto COMPUTE = [&](int bo) {
    const short* As = (const short*)(lds + bo);
    const short* Bs = (const short*)(lds + bo + 8192);
    short8 af[4];
#pragma unroll
    for (int mi = 0; mi < 4; ++mi) {
      int row = wr * 64 + mi * 16 + lr;
      int k = lk ^ (((row >> 1) & 3) << 3);
      af[mi] = *(const short8*)(&As[row * 32 + k]);
    }
#pragma unroll
    for (int ni = 0; ni < 10; ++ni) {
      int brow = wc * 160 + ni * 16 + lr;
      int k = lk ^ (((brow >> 1) & 3) << 3);
      short8 bf_ = *(const short8*)(&Bs[brow * 32 + k]);
#pragma unroll
      for (int mi = 0; mi < 4; ++mi)
        acc[mi][ni] = __builtin_amdgcn_mfma_f32_16x16x32_bf16(
            af[mi], bf_, acc[mi][ni], 0, 0, 0);
    }
  };

  STAGE(0, 0);
  __syncthreads();
  for (int t = 0; t < 16; t += 2) {
    STAGE(BUF1, (t + 1) * 32);
    COMPUTE(0);
    __syncthreads();
    if (t < 14) STAGE(0, (t + 2) * 32);
    COMPUTE(BUF1);
    __syncthreads();
  }

  // ---- fused transform epilogue: eight 16-row quarters ----
  float* plds = (float*)lds;                 // [16][PSTR]
  float* xo  = out;
  float* ldo = out + (size_t)NROWS * 64;
#pragma unroll
  for (int q = 0; q < 8; ++q) {
    if (q) __syncthreads();
    if (wr == (q >> 2)) {
      constexpr int MI_SHIFT = 0; (void)MI_SHIFT;
#pragma unroll
      for (int ni = 0; ni < 10; ++ni) {
        int col = wc * 160 + ni * 16 + lr;
        float bv = b3c[col];
#pragma unroll
        for (int j = 0; j < 4; ++j) {
          plds[(hi * 4 + j) * PSTR + col] = acc[q & 3][ni][j] + bv;  // q compile-time
        }
      }
    }
    __syncthreads();
    {
      int rl = tid >> 5, j = tid & 31;
      const float* p = plds + rl * PSTR;
      int grow = m0 + q * 16 + rl;

      float lg[8];
#pragma unroll
      for (int k = 0; k < 8; ++k) lg[k] = p[64 + k];
      float mx = lg[0];
#pragma unroll
      for (int k = 1; k < 8; ++k) mx = fmaxf(mx, lg[k]);
      float wgt[8], wsum = 0.0f;
#pragma unroll
      for (int k = 0; k < 8; ++k) { wgt[k] = __expf(lg[k] - mx); wsum += wgt[k]; }

      float xd = x[(size_t)grow * 64 + 32 + j];
      float zs = 0.0f, ps = 0.0f;
#pragma unroll
      for (int k = 0; k < 8; ++k) {
        float mu   = p[96 + k * 32 + j];
        float lstd = p[352 + k * 32 + j];
        float istd = __expf(-lstd);
        float u = (xd - mu) * istd;
        float x2 = 0.5f * u * u;                 // = (u/sqrt2)^2
        float e  = __expf(-x2);                  // e^{-u^2/2}
        ps += wgt[k] * e * istd;
        // 0.5*erfc(|u|/sqrt2), NR rational approx (rel err < 1.2e-7), shares x2:
        float ax = fabsf(u) * 0.70710678118654752f;
        float t_ = fastrcp(fmaf(0.5f, ax, 1.0f));
        float poly = -1.26551223f + t_*(1.00002368f + t_*(0.37409196f +
                     t_*(0.09678418f + t_*(-0.18628806f + t_*(0.27886807f +
                     t_*(-1.13520398f + t_*(1.48851587f + t_*(-0.82215223f +
                     t_*0.17087277f))))))));
        float erfc_half = 0.5f * t_ * __expf(poly - x2);
        float cdf = (u >= 0.0f) ? 1.0f - erfc_half : erfc_half;
        zs += wgt[k] * cdf;
      }
      float winv = fastrcp(wsum);
      float z  = zs * winv;
      float pm = ps * winv * 0.39894228040143268f;
      float logz = __logf(z), log1mz = __logf(1.0f - z);
      float ls = p[j], bv = p[32 + j];
      float outv = (logz - log1mz) * __expf(ls) + bv;
      float ld = __logf(pm) - logz - log1mz + ls;

      size_t base = (size_t)grow * 64;
      xo[base + j]       = x[base + j];
      xo[base + 32 + j]  = outv;
      ldo[base + j]      = 0.0f;
      ldo[base + 32 + j] = ld;
    }
  }
}

extern "C" void kernel_launch(void* const* d_in, const int* in_sizes, int n_in,
                              void* d_out, int out_size, void* d_ws, size_t ws_size,
                              hipStream_t stream) {
  const float* x  = (const float*)d_in[0];
  const float* W1 = (const float*)d_in[1];
  const float* b1 = (const float*)d_in[2];
  const float* W2 = (const float*)d_in[3];
  const float* b2 = (const float*)d_in[4];
  const float* W3 = (const float*)d_in[5];
  const float* b3 = (const float*)d_in[6];
  char* ws = (char*)d_ws;

  short* xc  = (short*)ws;                          // 4 MB   bf16 [65536][32]
  short* h1  = (short*)(ws + 4194304);              // 64 MB  bf16 [65536][512]
  short* h2  = (short*)(ws + 71303168);             // 64 MB  bf16 [65536][512]
  short* w1t = (short*)(ws + 138412032);            // 32 KB  bf16 [512][32]
  short* w2t = (short*)(ws + 138444800);            // 512 KB bf16 [512][512]
  short* w3t = (short*)(ws + 138969088);            // 640 KB bf16 [640][512]
  float* b3c = (float*)(ws + 139624448);            // 2.5 KB fp32 [640]
  float* out = (float*)d_out;

  prep_x_kernel<<<(NROWS * 4) / 256, 256, 0, stream>>>(x, xc);
  {
    int total = 512 * 32 + 512 * 512 + NCOMPACT * 512 + NCOMPACT;
    prep_w_kernel<<<(total + 255) / 256, 256, 0, stream>>>(W1, W2, W3, b3, w1t, w2t, w3t, b3c);
  }
  gemm_kernel<32, 4, true, true><<<2048, 256, 0, stream>>>(xc, w1t, b1, h1, 32, 512);
  gemm_kernel<64, 4, true, true><<<2048, 256, 0, stream>>>(h1, w2t, b2, h2, 512, 512);
  gemm3_fused_kernel<<<NROWS / 128, 512, 0, stream>>>(h2, w3t, b3c, x, out);
}

// Round 6
// 145.151 us; speedup vs baseline: 1.4598x; 1.0111x over previous
//
#include <hip/hip_runtime.h>

typedef short short8 __attribute__((ext_vector_type(8)));
typedef float f32x4 __attribute__((ext_vector_type(4)));

#define NROWS 65536        // B*T = 32*2048
#define NCOMPACT 640       // compacted+padded OUT columns

__device__ __forceinline__ short f2bf(float f) {
  union { float f; unsigned u; } c; c.f = f;
  unsigned r = (c.u + 0x7fffu + ((c.u >> 16) & 1u)) >> 16;
  return (short)r;
}

__device__ __forceinline__ float fastrcp(float a) {
  float r; asm("v_rcp_f32 %0, %1" : "=v"(r) : "v"(a)); return r;
}

// Map compacted column n -> original W3/b3 column (or -1 for zero pad).
__device__ __forceinline__ int w3col(int n) {
  if (n < 32)  return 32 + n;
  if (n < 64)  return 96 + (n - 32);
  if (n < 72)  return 128 + (n - 64);
  if (n < 96)  return -1;
  if (n < 352) { int q = n - 96;  return 168 + (q >> 5) * 64 + (q & 31); }
  if (n < 608) { int q = n - 352; return 680 + (q >> 5) * 64 + (q & 31); }
  return -1;
}

__global__ __launch_bounds__(256) void prep_x_kernel(const float* __restrict__ x,
                                                     short* __restrict__ xc) {
  int t = blockIdx.x * 256 + threadIdx.x;
  if (t >= NROWS * 4) return;
  int row = t >> 2, seg = t & 3;
  const float* src = x + (size_t)row * 64 + seg * 8;
  short8 v;
#pragma unroll
  for (int i = 0; i < 8; ++i) v[i] = f2bf(src[i]);
  *(short8*)(xc + (size_t)row * 32 + seg * 8) = v;
}

__global__ __launch_bounds__(256) void prep_w_kernel(
    const float* __restrict__ W1, const float* __restrict__ W2,
    const float* __restrict__ W3, const float* __restrict__ b3,
    short* __restrict__ w1t, short* __restrict__ w2t,
    short* __restrict__ w3t, float* __restrict__ b3c) {
  const int NW1 = 512 * 32, NW2 = 512 * 512, NW3 = NCOMPACT * 512;
  int t = blockIdx.x * 256 + threadIdx.x;
  if (t < NW1) {
    int n = t >> 5, k = t & 31;
    w1t[t] = f2bf(W1[k * 512 + n]);
  } else if (t < NW1 + NW2) {
    int i = t - NW1; int n = i >> 9, k = i & 511;
    w2t[i] = f2bf(W2[k * 512 + n]);
  } else if (t < NW1 + NW2 + NW3) {
    int i = t - NW1 - NW2; int n = i >> 9, k = i & 511;
    int c = w3col(n);
    w3t[i] = (c >= 0) ? f2bf(W3[(size_t)k * 1160 + c]) : (short)0;
  } else if (t < NW1 + NW2 + NW3 + NCOMPACT) {
    int n = t - NW1 - NW2 - NW3;
    int c = w3col(n);
    b3c[n] = (c >= 0) ? b3[c] : 0.0f;
  }
}

// C[M][N] = act(A[M][K] @ B^T[N][K] + bias[N]); 128x128 tile, 4 waves.
// 1D grid + bijective XCD-chunked swizzle, n-fastest work order.
template <int BK, int NT, bool RELU, bool OUT_BF16>
__global__ __launch_bounds__(256) void gemm_kernel(
    const short* __restrict__ A, const short* __restrict__ B,
    const float* __restrict__ bias, void* __restrict__ C, int K, int N) {
  __shared__ short As[128 * BK];
  __shared__ short Bs[128 * BK];
  const int tid = threadIdx.x;
  const int cpx = gridDim.x >> 3;
  const int s = blockIdx.x;
  const int w = (s & 7) * cpx + (s >> 3);
  const int m0 = (w / NT) * 128, n0 = (w % NT) * 128;
  const int lane = tid & 63, wid = tid >> 6;
  const int wm = (wid >> 1) * 64, wn = (wid & 1) * 64;
  const int lr = lane & 15, lk = (lane >> 4) * 8;
  constexpr int CPR = BK / 8;
  constexpr int SWM = CPR - 1;
  constexpr int NCHUNK = 128 * CPR;

  f32x4 acc[4][4] = {};

  for (int kt = 0; kt < K; kt += BK) {
    for (int base = wid * 64; base < NCHUNK; base += 256) {
      int c = base + lane;
      int row = c / CPR;
      int kb = (c % CPR) << 4;
      int skb = kb ^ ((row & SWM) << 4);
      const char* ga = (const char*)(A + (size_t)(m0 + row) * K + kt) + skb;
      const char* gb = (const char*)(B + (size_t)(n0 + row) * K + kt) + skb;
      __builtin_amdgcn_global_load_lds(
          (const __attribute__((address_space(1))) void*)ga,
          (__attribute__((address_space(3))) void*)((char*)As + (size_t)base * 16), 16, 0, 0);
      __builtin_amdgcn_global_load_lds(
          (const __attribute__((address_space(1))) void*)gb,
          (__attribute__((address_space(3))) void*)((char*)Bs + (size_t)base * 16), 16, 0, 0);
    }
    __syncthreads();
#pragma unroll
    for (int ks = 0; ks < BK; ks += 32) {
      short8 af[4], bf_[4];
#pragma unroll
      for (int mi = 0; mi < 4; ++mi) {
        int row = wm + mi * 16 + lr;
        int k = (ks + lk) ^ ((row & SWM) << 3);
        af[mi] = *(const short8*)(&As[row * BK + k]);
      }
#pragma unroll
      for (int ni = 0; ni < 4; ++ni) {
        int row = wn + ni * 16 + lr;
        int k = (ks + lk) ^ ((row & SWM) << 3);
        bf_[ni] = *(const short8*)(&Bs[row * BK + k]);
      }
#pragma unroll
      for (int mi = 0; mi < 4; ++mi)
#pragma unroll
        for (int ni = 0; ni < 4; ++ni)
          acc[mi][ni] = __builtin_amdgcn_mfma_f32_16x16x32_bf16(
              af[mi], bf_[ni], acc[mi][ni], 0, 0, 0);
    }
    __syncthreads();
  }

#pragma unroll
  for (int ni = 0; ni < 4; ++ni) {
    int col = n0 + wn + ni * 16 + lr;
    float bv = bias[col];
#pragma unroll
    for (int mi = 0; mi < 4; ++mi) {
#pragma unroll
      for (int j = 0; j < 4; ++j) {
        int row = m0 + wm + mi * 16 + (lane >> 4) * 4 + j;
        float v = acc[mi][ni][j] + bv;
        if (RELU) v = fmaxf(v, 0.0f);
        if (OUT_BF16) ((short*)C)[(size_t)row * N + col] = f2bf(v);
        else          ((float*)C)[(size_t)row * N + col] = v;
      }
    }
  }
}

// GEMM3 + mixture-CDF transform, fused. Block = 128 rows x 640 cols, 16 waves (4Mx4N),
// wave = 32 rows x 160 cols -> acc[2][10] = 80 regs (occupancy: 4 waves/SIMD at <=128).
// Double-buffered BK=32 global_load_lds staging (2 x 48KB LDS), source-side XOR
// swizzle g(row)=(row>>1)&3. STAGE(next) issued before COMPUTE(cur).
// Epilogue: four 32-row phases: wave-group wr==p dumps acc -> [32][644] f32 LDS tile
// (82KB) -> all 1024 threads transform one (row, j) -> direct d_out write.
#define PSTR 644
#define BUF1 49152
__global__ __launch_bounds__(1024, 4) void gemm3_fused_kernel(
    const short* __restrict__ A,      // h2 bf16 [NROWS][512]
    const short* __restrict__ Bw,     // w3t bf16 [640][512]
    const float* __restrict__ b3c,    // [640]
    const float* __restrict__ x,      // fp32 [NROWS][64]
    float* __restrict__ out) {
  __shared__ __attribute__((aligned(16))) char lds[98304];
  const int tid = threadIdx.x;
  const int m0 = blockIdx.x * 128;
  const int lane = tid & 63, wid = tid >> 6;   // wid 0..15
  const int wr = wid >> 2, wc = wid & 3;       // wr: 32-row group, wc: 160-col group
  const int lr = lane & 15, hi = lane >> 4, lk = hi * 8;

  f32x4 acc[2][10] = {};

  auto STAGE = [&](int bo, int kt) {
#pragma unroll
    for (int base = wid * 64; base < 3072; base += 1024) {
      int c = base + lane;
      char* dst = lds + bo + (size_t)base * 16;   // HW adds lane*16
      if (base < 512) {                           // A chunks [0,512)
        int row = c >> 2;
        int skb = ((c & 3) ^ ((row >> 1) & 3)) << 4;
        const char* ga = (const char*)(A + (size_t)(m0 + row) * 512 + kt) + skb;
        __builtin_amdgcn_global_load_lds(
            (const __attribute__((address_space(1))) void*)ga,
            (__attribute__((address_space(3))) void*)dst, 16, 0, 0);
      } else {                                    // B chunks [512,3072)
        int q = c - 512;
        int row = q >> 2;
        int skb = ((q & 3) ^ ((row >> 1) & 3)) << 4;
        const char* gb = (const char*)(Bw + (size_t)row * 512 + kt) + skb;
        __builtin_amdgcn_global_load_lds(
            (const __attribute__((address_space(1))) void*)gb,
            (__attribute__((address_space(3))) void*)dst, 16, 0, 0);
      }
    }
  };

  auto COMPUTE = [&](int bo) {
    const short* As = (const short*)(lds + bo);
    const short* Bs = (const short*)(lds + bo + 8192);
    short8 af[2];
#pragma unroll
    for (int mi = 0; mi < 2; ++mi) {
      int row = wr * 32 + mi * 16 + lr;
      int k = lk ^ (((row >> 1) & 3) << 3);
      af[mi] = *(const short8*)(&As[row * 32 + k]);
    }
#pragma unroll
    for (int ni = 0; ni < 10; ++ni) {
      int brow = wc * 160 + ni * 16 + lr;
      int k = lk ^ (((brow >> 1) & 3) << 3);
      short8 bf_ = *(const short8*)(&Bs[brow * 32 + k]);
      acc[0][ni] = __builtin_amdgcn_mfma_f32_16x16x32_bf16(af[0], bf_, acc[0][ni], 0, 0, 0);
      acc[1][ni] = __builtin_amdgcn_mfma_f32_16x16x32_bf16(af[1], bf_, acc[1][ni], 0, 0, 0);
    }
  };

  STAGE(0, 0);
  __syncthreads();
  for (int t = 0; t < 16; t += 2) {
    STAGE(BUF1, (t + 1) * 32);
    COMPUTE(0);
    __syncthreads();
    if (t < 14) STAGE(0, (t + 2) * 32);
    COMPUTE(BUF1);
    __syncthreads();
  }

  // ---- fused transform epilogue: four 32-row phases ----
  float* plds = (float*)lds;                 // [32][PSTR] f32 = 82432 B
  float* xo  = out;
  float* ldo = out + (size_t)NROWS * 64;
#pragma unroll
  for (int p = 0; p < 4; ++p) {
    if (p) __syncthreads();
    if (wr == p) {
#pragma unroll
      for (int mi = 0; mi < 2; ++mi) {
#pragma unroll
        for (int ni = 0; ni < 10; ++ni) {
          int col = wc * 160 + ni * 16 + lr;
          float bv = b3c[col];
#pragma unroll
          for (int j = 0; j < 4; ++j)
            plds[(mi * 16 + hi * 4 + j) * PSTR + col] = acc[mi][ni][j] + bv;
        }
      }
    }
    __syncthreads();
    {
      int rl = tid >> 5, j = tid & 31;       // rl 0..31, j 0..31
      const float* p_ = plds + rl * PSTR;
      int grow = m0 + p * 32 + rl;

      float lg[8];
#pragma unroll
      for (int k = 0; k < 8; ++k) lg[k] = p_[64 + k];
      float mx = lg[0];
#pragma unroll
      for (int k = 1; k < 8; ++k) mx = fmaxf(mx, lg[k]);
      float wgt[8], wsum = 0.0f;
#pragma unroll
      for (int k = 0; k < 8; ++k) { wgt[k] = __expf(lg[k] - mx); wsum += wgt[k]; }

      float xd = x[(size_t)grow * 64 + 32 + j];
      float zs = 0.0f, ps = 0.0f;
#pragma unroll
      for (int k = 0; k < 8; ++k) {
        float mu   = p_[96 + k * 32 + j];
        float lstd = p_[352 + k * 32 + j];
        float istd = __expf(-lstd);
        float u = (xd - mu) * istd;
        float x2 = 0.5f * u * u;                 // = (u/sqrt2)^2
        float e  = __expf(-x2);                  // e^{-u^2/2}
        ps += wgt[k] * e * istd;
        // 0.5*erfc(|u|/sqrt2), NR rational approx (rel err < 1.2e-7), shares x2:
        float ax = fabsf(u) * 0.70710678118654752f;
        float t_ = fastrcp(fmaf(0.5f, ax, 1.0f));
        float poly = -1.26551223f + t_*(1.00002368f + t_*(0.37409196f +
                     t_*(0.09678418f + t_*(-0.18628806f + t_*(0.27886807f +
                     t_*(-1.13520398f + t_*(1.48851587f + t_*(-0.82215223f +
                     t_*0.17087277f))))))));
        float erfc_half = 0.5f * t_ * __expf(poly - x2);
        float cdf = (u >= 0.0f) ? 1.0f - erfc_half : erfc_half;
        zs += wgt[k] * cdf;
      }
      float winv = fastrcp(wsum);
      float z  = zs * winv;
      float pm = ps * winv * 0.39894228040143268f;
      float logz = __logf(z), log1mz = __logf(1.0f - z);
      float ls = p_[j], bv = p_[32 + j];
      float outv = (logz - log1mz) * __expf(ls) + bv;
      float ld = __logf(pm) - logz - log1mz + ls;

      size_t base = (size_t)grow * 64;
      xo[base + j]       = x[base + j];
      xo[base + 32 + j]  = outv;
      ldo[base + j]      = 0.0f;
      ldo[base + 32 + j] = ld;
    }
  }
}

extern "C" void kernel_launch(void* const* d_in, const int* in_sizes, int n_in,
                              void* d_out, int out_size, void* d_ws, size_t ws_size,
                              hipStream_t stream) {
  const float* x  = (const float*)d_in[0];
  const float* W1 = (const float*)d_in[1];
  const float* b1 = (const float*)d_in[2];
  const float* W2 = (const float*)d_in[3];
  const float* b2 = (const float*)d_in[4];
  const float* W3 = (const float*)d_in[5];
  const float* b3 = (const float*)d_in[6];
  char* ws = (char*)d_ws;

  short* xc  = (short*)ws;                          // 4 MB   bf16 [65536][32]
  short* h1  = (short*)(ws + 4194304);              // 64 MB  bf16 [65536][512]
  short* h2  = (short*)(ws + 71303168);             // 64 MB  bf16 [65536][512]
  short* w1t = (short*)(ws + 138412032);            // 32 KB  bf16 [512][32]
  short* w2t = (short*)(ws + 138444800);            // 512 KB bf16 [512][512]
  short* w3t = (short*)(ws + 138969088);            // 640 KB bf16 [640][512]
  float* b3c = (float*)(ws + 139624448);            // 2.5 KB fp32 [640]
  float* out = (float*)d_out;

  prep_x_kernel<<<(NROWS * 4) / 256, 256, 0, stream>>>(x, xc);
  {
    int total = 512 * 32 + 512 * 512 + NCOMPACT * 512 + NCOMPACT;
    prep_w_kernel<<<(total + 255) / 256, 256, 0, stream>>>(W1, W2, W3, b3, w1t, w2t, w3t, b3c);
  }
  gemm_kernel<32, 4, true, true><<<2048, 256, 0, stream>>>(xc, w1t, b1, h1, 32, 512);
  gemm_kernel<64, 4, true, true><<<2048, 256, 0, stream>>>(h1, w2t, b2, h2, 512, 512);
  gemm3_fused_kernel<<<NROWS / 128, 1024, 0, stream>>>(h2, w3t, b3c, x, out);
}